// Round 1
// baseline (95.401 us; speedup 1.0000x reference)
//
#include <hip/hip_runtime.h>

// IndRNN only-recurrent: h_t = relu(x_t + w * h_{t-1}), elementwise over [B,H],
// sequential over T. Pure HBM-streaming problem: 256 MiB in + 256 MiB out.
//
// Decomposition: each thread owns VEC=4 consecutive h-columns (one float4).
// 65536 columns / 4 = 16384 threads = 256 blocks x 64 threads -> 1 wave/CU on
// all 256 CUs. Serial dependence lives in registers; loads are prefetched
// DEPTH timesteps ahead (addresses independent of the h-chain).

constexpr int T     = 1024;
constexpr int B     = 64;
constexpr int H     = 1024;
constexpr int N     = B * H;        // 65536 elements per timestep
constexpr int VEC   = 4;
constexpr int NT    = N / VEC;      // 16384 float4's per timestep
constexpr int BLOCK = 64;
constexpr int GRID  = NT / BLOCK;   // 256 blocks -> 1 per CU
constexpr int DEPTH = 16;           // 16 KiB outstanding per CU (> ~9.6 KiB needed)

__global__ __launch_bounds__(BLOCK) void indrnn_kernel(
    const float4* __restrict__ x,    // [T][NT] as float4
    const float4* __restrict__ h0,   // [NT]
    const float*  __restrict__ w,    // [H]
    float4*       __restrict__ out)  // [T][NT]
{
    const int tid = blockIdx.x * BLOCK + threadIdx.x;   // 0..NT-1
    const int e   = tid * VEC;                          // first element index

    // All 4 elements of this thread share the same batch row; weight index is
    // (e % H)..(e % H + 3), 16B-aligned since VEC | H.
    const float4 wv = *reinterpret_cast<const float4*>(w + (e & (H - 1)));
    float4 h = h0[tid];

    const float4* xp = x + tid;
    float4*       op = out + tid;

    // Prefetch pipeline: buf[i] holds x_{t+i}. All indices compile-time
    // constants after unroll (registers, not scratch).
    float4 buf[DEPTH];
#pragma unroll
    for (int i = 0; i < DEPTH; ++i) buf[i] = xp[i * NT];

    int t = 0;
    for (; t < T - DEPTH; t += DEPTH) {
#pragma unroll
        for (int i = 0; i < DEPTH; ++i) {
            const float4 xv = buf[i];
            buf[i] = xp[(t + DEPTH + i) * NT];   // issue next load early
            h.x = fmaxf(fmaf(h.x, wv.x, xv.x), 0.0f);
            h.y = fmaxf(fmaf(h.y, wv.y, xv.y), 0.0f);
            h.z = fmaxf(fmaf(h.z, wv.z, xv.z), 0.0f);
            h.w = fmaxf(fmaf(h.w, wv.w, xv.w), 0.0f);
            op[(t + i) * NT] = h;
        }
    }
    // Tail: last DEPTH timesteps, no prefetch.
#pragma unroll
    for (int i = 0; i < DEPTH; ++i) {
        const float4 xv = buf[i];
        h.x = fmaxf(fmaf(h.x, wv.x, xv.x), 0.0f);
        h.y = fmaxf(fmaf(h.y, wv.y, xv.y), 0.0f);
        h.z = fmaxf(fmaf(h.z, wv.z, xv.z), 0.0f);
        h.w = fmaxf(fmaf(h.w, wv.w, xv.w), 0.0f);
        op[(t + i) * NT] = h;
    }
}

extern "C" void kernel_launch(void* const* d_in, const int* in_sizes, int n_in,
                              void* d_out, int out_size, void* d_ws, size_t ws_size,
                              hipStream_t stream) {
    const float4* x  = (const float4*)d_in[0];  // input  [T,B,H] fp32
    const float4* h0 = (const float4*)d_in[1];  // h0     [B,H]   fp32
    const float*  w  = (const float*)d_in[2];   // weight [H]     fp32
    float4* out = (float4*)d_out;               // output [T,B,H] fp32

    indrnn_kernel<<<GRID, BLOCK, 0, stream>>>(x, h0, w, out);
}